// Round 7
// baseline (110.164 us; speedup 1.0000x reference)
//
#include <hip/hip_runtime.h>
#include <math.h>

#define KW 7
#define PADW 12
#define BATCH 8
#define CIN 128
#define COUT 256
#define LEN 4096
#define L2V 4108
#define NQKV 768
#define KCONV 896
#define PTILE 64

typedef unsigned short u16;
typedef short v8s __attribute__((ext_vector_type(8)));
typedef float v4f __attribute__((ext_vector_type(4)));

// 2-bit chunk swizzle key from row bits 0..2 (keeps ds_read_b128 <=2-way)
#define KEY3(r) ((((r) & 3) ^ (((r) >> 2) & 1)))

__device__ __forceinline__ u16 f2bf(float f) {
  unsigned int x = __float_as_uint(f);
  x += 0x7fffu + ((x >> 16) & 1u);
  return (u16)(x >> 16);
}
__device__ __forceinline__ float bf2f(u16 u) {
  return __uint_as_float(((unsigned int)u) << 16);
}

__device__ __forceinline__ void gll16(const void* g, void* l) {
  __builtin_amdgcn_global_load_lds(
      (const __attribute__((address_space(1))) void*)g,
      (__attribute__((address_space(3))) void*)l, 16, 0, 0);
}

#define MFMA16(ACC, AA, BB)                                                    \
  { _Pragma("unroll") for (int fi_ = 0; fi_ < 4; ++fi_)                        \
    _Pragma("unroll") for (int fj_ = 0; fj_ < 4; ++fj_)                        \
      ACC[fi_][fj_] = __builtin_amdgcn_mfma_f32_16x16x32_bf16(                 \
          AA[fi_], BB[fj_], ACC[fi_][fj_], 0, 0, 0); }

// ---------------------------------------------------------------------------
// prep 1: weight norm -> wt[c][t][ci] bf16  (k = t*128+ci contiguous per c)
// ---------------------------------------------------------------------------
__global__ __launch_bounds__(256) void prep_wn(
    const float* __restrict__ v, const float* __restrict__ g,
    u16* __restrict__ wt)
{
  const int c = blockIdx.x;
  const float* vo = v + (size_t)c * (CIN * KW);
  float s = 0.f;
  for (int i = threadIdx.x; i < CIN * KW; i += 256) { float t = vo[i]; s += t * t; }
#pragma unroll
  for (int off = 1; off < 64; off <<= 1) s += __shfl_xor(s, off);
  __shared__ float red[4];
  if ((threadIdx.x & 63) == 0) red[threadIdx.x >> 6] = s;
  __syncthreads();
  const float tot = red[0] + red[1] + red[2] + red[3];
  const float scale = g[c] / sqrtf(tot);
  for (int i = threadIdx.x; i < CIN * KW; i += 256) {
    const int ci = i / 7, t = i - ci * 7;
    wt[((size_t)c * KW + t) * CIN + ci] = f2bf(vo[i] * scale);
  }
}

// ---------------------------------------------------------------------------
// prep 2: cast qw/pw/dw to bf16
// ---------------------------------------------------------------------------
__global__ __launch_bounds__(256) void prep_cast(
    const float* __restrict__ qw, const float* __restrict__ pw,
    const float* __restrict__ dw, u16* __restrict__ qwb,
    u16* __restrict__ pwb, u16* __restrict__ dwb)
{
  const int i4 = (blockIdx.x * 256 + threadIdx.x) * 4;
  const float* src; u16* dst; int off;
  if (i4 < 196608)      { src = qw; dst = qwb; off = i4; }
  else if (i4 < 262144) { src = pw; dst = pwb; off = i4 - 196608; }
  else                  { src = dw; dst = dwb; off = i4 - 262144; }
  const float4 vv = *(const float4*)(src + off);
  *(ushort4*)(dst + off) = make_ushort4(f2bf(vv.x), f2bf(vv.y), f2bf(vv.z), f2bf(vv.w));
}

// ---------------------------------------------------------------------------
// prep 3: zero xT pad rows 0..11; fill qkv pad rows 0..11 with qb bias
// ---------------------------------------------------------------------------
__global__ __launch_bounds__(256) void zero_fill(
    u16* __restrict__ xT, u16* __restrict__ qkv, const float* __restrict__ qb)
{
  const int idx = blockIdx.x * 256 + threadIdx.x;   // < 86016
  if (idx < BATCH * PADW * CIN) {                   // 12288
    const int b = idx / (PADW * CIN), r = idx - b * (PADW * CIN);
    xT[(size_t)b * L2V * CIN + r] = 0;
  } else {
    const int k = idx - BATCH * PADW * CIN;         // < 73728
    const int b = k / (PADW * NQKV), r2 = k - b * (PADW * NQKV);
    const int row = r2 / NQKV, n = r2 - row * NQKV;
    qkv[((size_t)b * L2V + row) * NQKV + n] = f2bf(qb[n]);
  }
}

// ---------------------------------------------------------------------------
// prep 4: transpose x[b][ci][p] f32 -> xT[b][12+p][ci] bf16
// ---------------------------------------------------------------------------
__global__ __launch_bounds__(256) void xpose(const float* __restrict__ x, u16* __restrict__ xT)
{
  const int b = blockIdx.y, p0 = blockIdx.x * 64;
  const int tx = threadIdx.x & 15, ty = threadIdx.x >> 4;
  const int p = p0 + ty * 4;
  const float* xb = x + (size_t)b * CIN * LEN;
  u16* xTb = xT + (size_t)b * L2V * CIN + (size_t)(PADW + p) * CIN;
#pragma unroll
  for (int half = 0; half < 2; ++half) {
    const int ci0 = half * 64 + tx * 4;
    float r[4][4];
#pragma unroll
    for (int i = 0; i < 4; ++i)
      *(float4*)r[i] = *(const float4*)(xb + (size_t)(ci0 + i) * LEN + p);
#pragma unroll
    for (int j = 0; j < 4; ++j)
      *(ushort4*)(xTb + (size_t)j * CIN + ci0) =
          make_ushort4(f2bf(r[0][j]), f2bf(r[1][j]), f2bf(r[2][j]), f2bf(r[3][j]));
  }
}

// ---------------------------------------------------------------------------
// FUSED conv + qkv.  Block owns 64 positions (p0..p0+63) of one batch.
// Phase A: h[64p][256c] = relu(conv+bias) built in LDS (never hits HBM).
// Phase B: qkv[m][768] = h @ qw^T + qb, weights streamed via global_load_lds.
// ---------------------------------------------------------------------------
__global__ __launch_bounds__(256, 2) void conv_qkv_fused(
    const u16* __restrict__ wt, const u16* __restrict__ xT,
    const float* __restrict__ c1b, const u16* __restrict__ qwb,
    const float* __restrict__ qb, u16* __restrict__ qkv)
{
  const int b = blockIdx.y;
  const int p0 = blockIdx.x * PTILE;
  const int tid = threadIdx.x;
  const int w = tid >> 6, lane = tid & 63;
  const int l15 = lane & 15, kg = lane >> 4;

  __shared__ u16 hA[PTILE * 256];       // 32 KB resident h tile (chunk-swizzled)
  __shared__ u16 sA[2][256 * 32];       // 32 KB A staging dbuf (also epilogue T)
  __shared__ u16 sB[2][PTILE * 32];     // 8 KB  B staging dbuf

  const int arow = tid >> 2, ach = tid & 3;
  const int akey = KEY3(arow);

  const u16* xTb = xT + (size_t)b * L2V * CIN + (size_t)p0 * CIN;

  v4f acc[4][4];
#pragma unroll
  for (int i = 0; i < 4; ++i)
#pragma unroll
    for (int j = 0; j < 4; ++j) acc[i][j] = (v4f){0.f, 0.f, 0.f, 0.f};

  // ---------------- phase A: conv, K = 896 (28 slabs of 32) ----------------
  auto stage_conv = [&](int s, int buf) {
    const int t = s >> 2, ci0 = (s & 3) << 5;
#pragma unroll
    for (int i = 0; i < 4; ++i) {
      const int row = i * 64 + arow;
      gll16(wt + (size_t)row * KCONV + t * CIN + ci0 + ((ach ^ akey) << 3),
            (void*)&sA[buf][(i * 256 + tid) * 8]);
    }
    gll16(xTb + (size_t)(2 * t + arow) * CIN + ci0 + ((ach ^ akey) << 3),
          (void*)&sB[buf][tid * 8]);
  };

  stage_conv(0, 0);
  __syncthreads();
  for (int s = 0; s < 28; ++s) {
    const int buf = s & 1;
    if (s < 27) stage_conv(s + 1, buf ^ 1);
    v8s a[4], bb[4];
#pragma unroll
    for (int f = 0; f < 4; ++f) {
      const int c = w * 64 + f * 16 + l15;
      a[f] = *(const v8s*)&sA[buf][c * 32 + ((kg ^ KEY3(c)) << 3)];
      const int p = f * 16 + l15;
      bb[f] = *(const v8s*)&sB[buf][p * 32 + ((kg ^ KEY3(p)) << 3)];
    }
    MFMA16(acc, a, bb)
    __syncthreads();
  }

  // conv epilogue: bias+relu -> hA (swizzled: chunk32' = chunk32 ^ (p&7))
#pragma unroll
  for (int fi = 0; fi < 4; ++fi) {
    const int cb = w * 64 + fi * 16 + kg * 4;
    const float4 bv = *(const float4*)(c1b + cb);
    const int ch32 = cb >> 3, off = cb & 7;
#pragma unroll
    for (int fj = 0; fj < 4; ++fj) {
      const int p = fj * 16 + l15;
      *(ushort4*)&hA[p * 256 + ((ch32 ^ (p & 7)) << 3) + off] = make_ushort4(
          f2bf(fmaxf(acc[fi][fj][0] + bv.x, 0.f)),
          f2bf(fmaxf(acc[fi][fj][1] + bv.y, 0.f)),
          f2bf(fmaxf(acc[fi][fj][2] + bv.z, 0.f)),
          f2bf(fmaxf(acc[fi][fj][3] + bv.w, 0.f)));
      acc[fi][fj] = (v4f){0.f, 0.f, 0.f, 0.f};
    }
  }

  // ---------------- phase B: qkv, 3 super-tiles of 256 n ----------------
  auto stage_qkv = [&](int st, int s, int buf) {
#pragma unroll
    for (int i = 0; i < 4; ++i) {
      const int row = i * 64 + arow;
      gll16(qwb + (size_t)(st * 256 + row) * COUT + (s << 5) + ((ach ^ akey) << 3),
            (void*)&sA[buf][(i * 256 + tid) * 8]);
    }
  };

  const size_t mg0 = (size_t)b * L2V + PADW + p0;
  for (int st = 0; st < 3; ++st) {
    stage_qkv(st, 0, 0);
    __syncthreads();
    for (int s = 0; s < 8; ++s) {
      const int buf = s & 1;
      if (s < 7) stage_qkv(st, s + 1, buf ^ 1);
      v8s a[4], bb[4];
#pragma unroll
      for (int f = 0; f < 4; ++f) {
        const int n = w * 64 + f * 16 + l15;
        a[f] = *(const v8s*)&sA[buf][n * 32 + ((kg ^ KEY3(n)) << 3)];
        const int p = f * 16 + l15;
        bb[f] = *(const v8s*)&hA[p * 256 + ((((s << 2) + kg) ^ (p & 7)) << 3)];
      }
      MFMA16(acc, a, bb)
      __syncthreads();
    }
    // epilogue: bias -> bf16 -> T (in sA region, swizzled) -> coalesced store
    u16* T = &sA[0][0];
#pragma unroll
    for (int fi = 0; fi < 4; ++fi) {
      const int nl = fi * 16 + kg * 4;
      const float4 bv = *(const float4*)(qb + st * 256 + w * 64 + nl);
      const int nlc = nl >> 3, noff = nl & 7;
#pragma unroll
      for (int fj = 0; fj < 4; ++fj) {
        const int m = fj * 16 + l15;
        *(ushort4*)&T[w * 4096 + m * 64 + ((nlc ^ (m & 7)) << 3) + noff] = make_ushort4(
            f2bf(acc[fi][fj][0] + bv.x), f2bf(acc[fi][fj][1] + bv.y),
            f2bf(acc[fi][fj][2] + bv.z), f2bf(acc[fi][fj][3] + bv.w));
        acc[fi][fj] = (v4f){0.f, 0.f, 0.f, 0.f};
      }
    }
    __syncthreads();
    {
      const int m = tid >> 2, c0 = (tid & 3) << 1;       // chunk-pair base
      u16* dst = qkv + (mg0 + m) * NQKV + st * 256;
#pragma unroll
      for (int q = 0; q < 4; ++q) {
        const int4 v0 = *(const int4*)&T[q * 4096 + m * 64 + (((c0 + 0) ^ (m & 7)) << 3)];
        const int4 v1 = *(const int4*)&T[q * 4096 + m * 64 + (((c0 + 1) ^ (m & 7)) << 3)];
        *(int4*)(dst + q * 64 + (c0 << 3)) = v0;
        *(int4*)(dst + q * 64 + (c0 << 3) + 8) = v1;
      }
    }
    __syncthreads();   // release T before next super-tile's prefetch
  }
}

// ---------------------------------------------------------------------------
// NATTEN attention on bf16 qkv. One wave per (b,j); lane owns 4 ch. (unchanged)
// ---------------------------------------------------------------------------
__global__ __launch_bounds__(256) void attn_bf16(
    const u16* __restrict__ qkv, const float* __restrict__ rpb,
    u16* __restrict__ ao)
{
  const int wid = (blockIdx.x << 2) + (threadIdx.x >> 6);
  const int lane = threadIdx.x & 63;
  const int b = wid >> 12;
  const int j = wid & 4095;
  const int r = j & 1, ii = j >> 1;
  int start = ii - 3;
  start = start < 0 ? 0 : start;
  start = start > 2047 ? 2047 : start;

  const u16* base = qkv + (size_t)b * L2V * NQKV;
  const ushort4 qv = *(const ushort4*)(base + (size_t)j * NQKV + 4 * lane);
  const float q0 = bf2f(qv.x) * 0.0625f, q1 = bf2f(qv.y) * 0.0625f;
  const float q2 = bf2f(qv.z) * 0.0625f, q3 = bf2f(qv.w) * 0.0625f;

  float sc[7];
  float mx = -1e30f;
#pragma unroll
  for (int t = 0; t < 7; ++t) {
    const int pos = r + 2 * (start + t);
    const ushort4 kv = *(const ushort4*)(base + (size_t)pos * NQKV + COUT + 4 * lane);
    float s = q0 * bf2f(kv.x) + q1 * bf2f(kv.y) + q2 * bf2f(kv.z) + q3 * bf2f(kv.w);
#pragma unroll
    for (int o = 1; o < 64; o <<= 1) s += __shfl_xor(s, o);
    s += rpb[start + t - ii + 6];
    sc[t] = s;
    mx = fmaxf(mx, s);
  }
  float sum = 0.f;
#pragma unroll
  for (int t = 0; t < 7; ++t) { sc[t] = __expf(sc[t] - mx); sum += sc[t]; }
  const float inv = 1.f / sum;

  float a0 = 0.f, a1 = 0.f, a2 = 0.f, a3 = 0.f;
#pragma unroll
  for (int t = 0; t < 7; ++t) {
    const int pos = r + 2 * (start + t);
    const ushort4 vv = *(const ushort4*)(base + (size_t)pos * NQKV + 2 * COUT + 4 * lane);
    const float wgt = sc[t] * inv;
    a0 += wgt * bf2f(vv.x); a1 += wgt * bf2f(vv.y);
    a2 += wgt * bf2f(vv.z); a3 += wgt * bf2f(vv.w);
  }
  *(ushort4*)(ao + ((size_t)(b * LEN + j)) * COUT + 4 * lane) =
      make_ushort4(f2bf(a0), f2bf(a1), f2bf(a2), f2bf(a3));
}

// ---------------------------------------------------------------------------
// fused proj + ds residual + double relu, gll-staged 128x128 tile.
// acc rows = l (A = activations), cols = o (B = weights); round-2 epilogue.
// ---------------------------------------------------------------------------
__global__ __launch_bounds__(256, 2) void projds_gll(
    const u16* __restrict__ ao, const u16* __restrict__ pwb,
    const float* __restrict__ pb, const u16* __restrict__ xT,
    const u16* __restrict__ dwb, const float* __restrict__ db,
    float* __restrict__ out)
{
  const int b = blockIdx.z;
  const int l0 = blockIdx.x * 128, o0 = blockIdx.y * 128;
  const int tid = threadIdx.x;
  const int w = tid >> 6, lane = tid & 63;
  const int l15 = lane & 15, kg = lane >> 4;
  const int wr = w >> 1, wc = w & 1;     // wr: l-half, wc: o-half

  __shared__ u16 sX[2][128 * 32];
  __shared__ u16 sW[2][128 * 32];

  const int arow = tid >> 2, ach = tid & 3;
  const int akey = KEY3(arow);
  const u16* aob = ao + (size_t)b * LEN * COUT;
  const u16* xTb = xT + ((size_t)b * L2V + PADW) * CIN;

  auto stage1 = [&](int s, int buf) {
#pragma unroll
    for (int i = 0; i < 2; ++i) {
      const int row = i * 64 + arow;
      const int sl = (ach ^ akey) << 3;
      gll16(aob + (size_t)(l0 + row) * COUT + (s << 5) + sl,
            (void*)&sX[buf][(i * 256 + tid) * 8]);
      gll16(pwb + (size_t)(o0 + row) * COUT + (s << 5) + sl,
            (void*)&sW[buf][(i * 256 + tid) * 8]);
    }
  };
  auto stage2 = [&](int s, int buf) {
#pragma unroll
    for (int i = 0; i < 2; ++i) {
      const int row = i * 64 + arow;
      const int sl = (ach ^ akey) << 3;
      gll16(xTb + (size_t)(l0 + row) * CIN + (s << 5) + sl,
            (void*)&sX[buf][(i * 256 + tid) * 8]);
      gll16(dwb + (size_t)(o0 + row) * CIN + (s << 5) + sl,
            (void*)&sW[buf][(i * 256 + tid) * 8]);
    }
  };

  v4f acc[4][4];
#pragma unroll
  for (int i = 0; i < 4; ++i)
#pragma unroll
    for (int j = 0; j < 4; ++j) acc[i][j] = (v4f){0.f, 0.f, 0.f, 0.f};

  stage1(0, 0);
  __syncthreads();
  for (int ss = 0; ss < 12; ++ss) {
    const int buf = ss & 1;
    if (ss < 7) stage1(ss + 1, buf ^ 1);
    else if (ss < 11) stage2(ss - 7, buf ^ 1);
    v8s a[4], bb[4];
#pragma unroll
    for (int f = 0; f < 4; ++f) {
      const int lr = wr * 64 + f * 16 + l15;
      a[f] = *(const v8s*)&sX[buf][lr * 32 + ((kg ^ KEY3(lr)) << 3)];
      const int orr = wc * 64 + f * 16 + l15;
      bb[f] = *(const v8s*)&sW[buf][orr * 32 + ((kg ^ KEY3(orr)) << 3)];
    }
    MFMA16(acc, a, bb)
    if (ss == 7) {
      // boundary: acc = relu(acc + pb[o])
#pragma unroll
      for (int fj = 0; fj < 4; ++fj) {
        const float pbv = pb[o0 + wc * 64 + fj * 16 + l15];
#pragma unroll
        for (int fi = 0; fi < 4; ++fi)
#pragma unroll
          for (int jj = 0; jj < 4; ++jj)
            acc[fi][fj][jj] = fmaxf(acc[fi][fj][jj] + pbv, 0.f);
      }
    }
    __syncthreads();
  }

  // epilogue (round-2 verbatim): +db, relu, f32 stores
  const int subl = kg;
#pragma unroll
  for (int fj = 0; fj < 4; ++fj) {
    const int o = o0 + wc * 64 + fj * 16 + l15;
    const float dbv = db[o];
    float* orow = out + ((size_t)(b * COUT + o)) * LEN;
#pragma unroll
    for (int fi = 0; fi < 4; ++fi) {
      const int lb = l0 + wr * 64 + fi * 16 + subl * 4;
      float v0 = acc[fi][fj][0] + dbv; v0 = v0 > 0.f ? v0 : 0.f;
      float v1 = acc[fi][fj][1] + dbv; v1 = v1 > 0.f ? v1 : 0.f;
      float v2 = acc[fi][fj][2] + dbv; v2 = v2 > 0.f ? v2 : 0.f;
      float v3 = acc[fi][fj][3] + dbv; v3 = v3 > 0.f ? v3 : 0.f;
      *(float4*)(orow + lb) = make_float4(v0, v1, v2, v3);
    }
  }
}

// ---------------------------------------------------------------------------
extern "C" void kernel_launch(void* const* d_in, const int* in_sizes, int n_in,
                              void* d_out, int out_size, void* d_ws, size_t ws_size,
                              hipStream_t stream)
{
  (void)in_sizes; (void)n_in; (void)out_size; (void)ws_size;
  const float* x   = (const float*)d_in[0];
  const float* c1v = (const float*)d_in[1];
  const float* c1g = (const float*)d_in[2];
  const float* c1b = (const float*)d_in[3];
  const float* qw  = (const float*)d_in[4];
  const float* qb  = (const float*)d_in[5];
  const float* rpb = (const float*)d_in[6];
  const float* pw  = (const float*)d_in[7];
  const float* pb  = (const float*)d_in[8];
  const float* dw  = (const float*)d_in[9];
  const float* db  = (const float*)d_in[10];
  float* out = (float*)d_out;

  char* ws = (char*)d_ws;
  u16* wt  = (u16*)(ws);                       // 458,752 B
  u16* qwb = (u16*)(ws + 458752);              // 393,216 B
  u16* pwb = (u16*)(ws + 851968);              // 131,072 B
  u16* dwb = (u16*)(ws + 983040);              //  65,536 B
  u16* xT  = (u16*)(ws + 1048576);             // 8,413,184 B
  u16* qkv = (u16*)(ws + 26288128);            // 50,479,104 B
  u16* ao  = (u16*)(ws + 76767232);            // 16,777,216 B

  prep_wn<<<COUT, 256, 0, stream>>>(c1v, c1g, wt);
  prep_cast<<<288, 256, 0, stream>>>(qw, pw, dw, qwb, pwb, dwb);
  zero_fill<<<336, 256, 0, stream>>>(xT, qkv, qb);
  xpose<<<dim3(LEN / 64, BATCH), 256, 0, stream>>>(x, xT);
  conv_qkv_fused<<<dim3(LEN / PTILE, BATCH), 256, 0, stream>>>(wt, xT, c1b, qwb, qb, qkv);
  attn_bf16<<<(BATCH * LEN) / 4, 256, 0, stream>>>(qkv, rpb, ao);
  projds_gll<<<dim3(LEN / 128, COUT / 128, BATCH), 256, 0, stream>>>(ao, pwb, pb, xT, dwb, db, out);
}

// Round 8
// 109.973 us; speedup vs baseline: 1.0017x; 1.0017x over previous
//
#include <hip/hip_runtime.h>
#include <math.h>

#define KW 7
#define PADW 12
#define BATCH 8
#define CIN 128
#define COUT 256
#define LEN 4096
#define L2V 4108
#define NQKV 768
#define KCONV 896
#define PTILE 64

typedef unsigned short u16;
typedef short v8s __attribute__((ext_vector_type(8)));
typedef float v4f __attribute__((ext_vector_type(4)));

// 2-bit chunk swizzle key from row bits 0..2 (keeps ds_read_b128 <=2-way)
#define KEY3(r) ((((r) & 3) ^ (((r) >> 2) & 1)))

__device__ __forceinline__ u16 f2bf(float f) {
  unsigned int x = __float_as_uint(f);
  x += 0x7fffu + ((x >> 16) & 1u);
  return (u16)(x >> 16);
}
__device__ __forceinline__ float bf2f(u16 u) {
  return __uint_as_float(((unsigned int)u) << 16);
}

__device__ __forceinline__ void gll16(const void* g, void* l) {
  __builtin_amdgcn_global_load_lds(
      (const __attribute__((address_space(1))) void*)g,
      (__attribute__((address_space(3))) void*)l, 16, 0, 0);
}

#define MFMA16(ACC, AA, BB)                                                    \
  { _Pragma("unroll") for (int fi_ = 0; fi_ < 4; ++fi_)                        \
    _Pragma("unroll") for (int fj_ = 0; fj_ < 4; ++fj_)                        \
      ACC[fi_][fj_] = __builtin_amdgcn_mfma_f32_16x16x32_bf16(                 \
          AA[fi_], BB[fj_], ACC[fi_][fj_], 0, 0, 0); }

// ---------------------------------------------------------------------------
// prep 1: weight norm -> wt[c][t][ci] bf16  (k = t*128+ci contiguous per c)
// ---------------------------------------------------------------------------
__global__ __launch_bounds__(256) void prep_wn(
    const float* __restrict__ v, const float* __restrict__ g,
    u16* __restrict__ wt)
{
  const int c = blockIdx.x;
  const float* vo = v + (size_t)c * (CIN * KW);
  float s = 0.f;
  for (int i = threadIdx.x; i < CIN * KW; i += 256) { float t = vo[i]; s += t * t; }
#pragma unroll
  for (int off = 1; off < 64; off <<= 1) s += __shfl_xor(s, off);
  __shared__ float red[4];
  if ((threadIdx.x & 63) == 0) red[threadIdx.x >> 6] = s;
  __syncthreads();
  const float tot = red[0] + red[1] + red[2] + red[3];
  const float scale = g[c] / sqrtf(tot);
  for (int i = threadIdx.x; i < CIN * KW; i += 256) {
    const int ci = i / 7, t = i - ci * 7;
    wt[((size_t)c * KW + t) * CIN + ci] = f2bf(vo[i] * scale);
  }
}

// ---------------------------------------------------------------------------
// prep 2: cast qw/pw/dw to bf16
// ---------------------------------------------------------------------------
__global__ __launch_bounds__(256) void prep_cast(
    const float* __restrict__ qw, const float* __restrict__ pw,
    const float* __restrict__ dw, u16* __restrict__ qwb,
    u16* __restrict__ pwb, u16* __restrict__ dwb)
{
  const int i4 = (blockIdx.x * 256 + threadIdx.x) * 4;
  const float* src; u16* dst; int off;
  if (i4 < 196608)      { src = qw; dst = qwb; off = i4; }
  else if (i4 < 262144) { src = pw; dst = pwb; off = i4 - 196608; }
  else                  { src = dw; dst = dwb; off = i4 - 262144; }
  const float4 vv = *(const float4*)(src + off);
  *(ushort4*)(dst + off) = make_ushort4(f2bf(vv.x), f2bf(vv.y), f2bf(vv.z), f2bf(vv.w));
}

// ---------------------------------------------------------------------------
// prep 3: zero xT pad rows 0..11; fill qkv pad rows 0..11 with qb bias
// ---------------------------------------------------------------------------
__global__ __launch_bounds__(256) void zero_fill(
    u16* __restrict__ xT, u16* __restrict__ qkv, const float* __restrict__ qb)
{
  const int idx = blockIdx.x * 256 + threadIdx.x;   // < 86016
  if (idx < BATCH * PADW * CIN) {                   // 12288
    const int b = idx / (PADW * CIN), r = idx - b * (PADW * CIN);
    xT[(size_t)b * L2V * CIN + r] = 0;
  } else {
    const int k = idx - BATCH * PADW * CIN;         // < 73728
    const int b = k / (PADW * NQKV), r2 = k - b * (PADW * NQKV);
    const int row = r2 / NQKV, n = r2 - row * NQKV;
    qkv[((size_t)b * L2V + row) * NQKV + n] = f2bf(qb[n]);
  }
}

// ---------------------------------------------------------------------------
// prep 4: transpose x[b][ci][p] f32 -> xT[b][12+p][ci] bf16
// ---------------------------------------------------------------------------
__global__ __launch_bounds__(256) void xpose(const float* __restrict__ x, u16* __restrict__ xT)
{
  const int b = blockIdx.y, p0 = blockIdx.x * 64;
  const int tx = threadIdx.x & 15, ty = threadIdx.x >> 4;
  const int p = p0 + ty * 4;
  const float* xb = x + (size_t)b * CIN * LEN;
  u16* xTb = xT + (size_t)b * L2V * CIN + (size_t)(PADW + p) * CIN;
#pragma unroll
  for (int half = 0; half < 2; ++half) {
    const int ci0 = half * 64 + tx * 4;
    float r[4][4];
#pragma unroll
    for (int i = 0; i < 4; ++i)
      *(float4*)r[i] = *(const float4*)(xb + (size_t)(ci0 + i) * LEN + p);
#pragma unroll
    for (int j = 0; j < 4; ++j)
      *(ushort4*)(xTb + (size_t)j * CIN + ci0) =
          make_ushort4(f2bf(r[0][j]), f2bf(r[1][j]), f2bf(r[2][j]), f2bf(r[3][j]));
  }
}

// ---------------------------------------------------------------------------
// FUSED conv + qkv.  Block owns 64 positions (p0..p0+63) of one batch.
// Phase A: h[64p][256c] = relu(conv+bias) built in LDS (never hits HBM).
// Phase B: qkv[m][768] = h @ qw^T + qb, weights streamed via global_load_lds.
// ---------------------------------------------------------------------------
__global__ __launch_bounds__(256, 2) void conv_qkv_fused(
    const u16* __restrict__ wt, const u16* __restrict__ xT,
    const float* __restrict__ c1b, const u16* __restrict__ qwb,
    const float* __restrict__ qb, u16* __restrict__ qkv)
{
  const int b = blockIdx.y;
  const int p0 = blockIdx.x * PTILE;
  const int tid = threadIdx.x;
  const int w = tid >> 6, lane = tid & 63;
  const int l15 = lane & 15, kg = lane >> 4;

  __shared__ u16 hA[PTILE * 256];       // 32 KB resident h tile (chunk-swizzled)
  __shared__ u16 sA[2][256 * 32];       // 32 KB A staging dbuf (also epilogue T)
  __shared__ u16 sB[2][PTILE * 32];     // 8 KB  B staging dbuf

  const int arow = tid >> 2, ach = tid & 3;
  const int akey = KEY3(arow);

  const u16* xTb = xT + (size_t)b * L2V * CIN + (size_t)p0 * CIN;

  v4f acc[4][4];
#pragma unroll
  for (int i = 0; i < 4; ++i)
#pragma unroll
    for (int j = 0; j < 4; ++j) acc[i][j] = (v4f){0.f, 0.f, 0.f, 0.f};

  // ---------------- phase A: conv, K = 896 (28 slabs of 32) ----------------
  auto stage_conv = [&](int s, int buf) {
    const int t = s >> 2, ci0 = (s & 3) << 5;
#pragma unroll
    for (int i = 0; i < 4; ++i) {
      const int row = i * 64 + arow;
      gll16(wt + (size_t)row * KCONV + t * CIN + ci0 + ((ach ^ akey) << 3),
            (void*)&sA[buf][(i * 256 + tid) * 8]);
    }
    gll16(xTb + (size_t)(2 * t + arow) * CIN + ci0 + ((ach ^ akey) << 3),
          (void*)&sB[buf][tid * 8]);
  };

  stage_conv(0, 0);
  __syncthreads();
  for (int s = 0; s < 28; ++s) {
    const int buf = s & 1;
    if (s < 27) stage_conv(s + 1, buf ^ 1);
    v8s a[4], bb[4];
#pragma unroll
    for (int f = 0; f < 4; ++f) {
      const int c = w * 64 + f * 16 + l15;
      a[f] = *(const v8s*)&sA[buf][c * 32 + ((kg ^ KEY3(c)) << 3)];
      const int p = f * 16 + l15;
      bb[f] = *(const v8s*)&sB[buf][p * 32 + ((kg ^ KEY3(p)) << 3)];
    }
    MFMA16(acc, a, bb)
    __syncthreads();
  }

  // conv epilogue: bias+relu -> hA (swizzled: chunk32' = chunk32 ^ (p&7))
#pragma unroll
  for (int fi = 0; fi < 4; ++fi) {
    const int cb = w * 64 + fi * 16 + kg * 4;
    const float4 bv = *(const float4*)(c1b + cb);
    const int ch32 = cb >> 3, off = cb & 7;
#pragma unroll
    for (int fj = 0; fj < 4; ++fj) {
      const int p = fj * 16 + l15;
      *(ushort4*)&hA[p * 256 + ((ch32 ^ (p & 7)) << 3) + off] = make_ushort4(
          f2bf(fmaxf(acc[fi][fj][0] + bv.x, 0.f)),
          f2bf(fmaxf(acc[fi][fj][1] + bv.y, 0.f)),
          f2bf(fmaxf(acc[fi][fj][2] + bv.z, 0.f)),
          f2bf(fmaxf(acc[fi][fj][3] + bv.w, 0.f)));
      acc[fi][fj] = (v4f){0.f, 0.f, 0.f, 0.f};
    }
  }

  // ---------------- phase B: qkv, 3 super-tiles of 256 n ----------------
  auto stage_qkv = [&](int st, int s, int buf) {
#pragma unroll
    for (int i = 0; i < 4; ++i) {
      const int row = i * 64 + arow;
      gll16(qwb + (size_t)(st * 256 + row) * COUT + (s << 5) + ((ach ^ akey) << 3),
            (void*)&sA[buf][(i * 256 + tid) * 8]);
    }
  };

  const size_t mg0 = (size_t)b * L2V + PADW + p0;
  for (int st = 0; st < 3; ++st) {
    stage_qkv(st, 0, 0);
    __syncthreads();
    for (int s = 0; s < 8; ++s) {
      const int buf = s & 1;
      if (s < 7) stage_qkv(st, s + 1, buf ^ 1);
      v8s a[4], bb[4];
#pragma unroll
      for (int f = 0; f < 4; ++f) {
        const int n = w * 64 + f * 16 + l15;
        a[f] = *(const v8s*)&sA[buf][n * 32 + ((kg ^ KEY3(n)) << 3)];
        const int p = f * 16 + l15;
        bb[f] = *(const v8s*)&hA[p * 256 + ((((s << 2) + kg) ^ (p & 7)) << 3)];
      }
      MFMA16(acc, a, bb)
      __syncthreads();
    }
    // epilogue: bias -> bf16 -> T (in sA region, swizzled) -> coalesced store
    u16* T = &sA[0][0];
#pragma unroll
    for (int fi = 0; fi < 4; ++fi) {
      const int nl = fi * 16 + kg * 4;
      const float4 bv = *(const float4*)(qb + st * 256 + w * 64 + nl);
      const int nlc = nl >> 3, noff = nl & 7;
#pragma unroll
      for (int fj = 0; fj < 4; ++fj) {
        const int m = fj * 16 + l15;
        *(ushort4*)&T[w * 4096 + m * 64 + ((nlc ^ (m & 7)) << 3) + noff] = make_ushort4(
            f2bf(acc[fi][fj][0] + bv.x), f2bf(acc[fi][fj][1] + bv.y),
            f2bf(acc[fi][fj][2] + bv.z), f2bf(acc[fi][fj][3] + bv.w));
        acc[fi][fj] = (v4f){0.f, 0.f, 0.f, 0.f};
      }
    }
    __syncthreads();
    {
      const int m = tid >> 2, c0 = (tid & 3) << 1;       // chunk-pair base
      u16* dst = qkv + (mg0 + m) * NQKV + st * 256;
#pragma unroll
      for (int q = 0; q < 4; ++q) {
        const int4 v0 = *(const int4*)&T[q * 4096 + m * 64 + (((c0 + 0) ^ (m & 7)) << 3)];
        const int4 v1 = *(const int4*)&T[q * 4096 + m * 64 + (((c0 + 1) ^ (m & 7)) << 3)];
        *(int4*)(dst + q * 64 + (c0 << 3)) = v0;
        *(int4*)(dst + q * 64 + (c0 << 3) + 8) = v1;
      }
    }
    __syncthreads();   // release T before next super-tile's prefetch
  }
}

// ---------------------------------------------------------------------------
// NATTEN attention on bf16 qkv. One wave per (b,j); lane owns 4 ch. (unchanged)
// ---------------------------------------------------------------------------
__global__ __launch_bounds__(256) void attn_bf16(
    const u16* __restrict__ qkv, const float* __restrict__ rpb,
    u16* __restrict__ ao)
{
  const int wid = (blockIdx.x << 2) + (threadIdx.x >> 6);
  const int lane = threadIdx.x & 63;
  const int b = wid >> 12;
  const int j = wid & 4095;
  const int r = j & 1, ii = j >> 1;
  int start = ii - 3;
  start = start < 0 ? 0 : start;
  start = start > 2047 ? 2047 : start;

  const u16* base = qkv + (size_t)b * L2V * NQKV;
  const ushort4 qv = *(const ushort4*)(base + (size_t)j * NQKV + 4 * lane);
  const float q0 = bf2f(qv.x) * 0.0625f, q1 = bf2f(qv.y) * 0.0625f;
  const float q2 = bf2f(qv.z) * 0.0625f, q3 = bf2f(qv.w) * 0.0625f;

  float sc[7];
  float mx = -1e30f;
#pragma unroll
  for (int t = 0; t < 7; ++t) {
    const int pos = r + 2 * (start + t);
    const ushort4 kv = *(const ushort4*)(base + (size_t)pos * NQKV + COUT + 4 * lane);
    float s = q0 * bf2f(kv.x) + q1 * bf2f(kv.y) + q2 * bf2f(kv.z) + q3 * bf2f(kv.w);
#pragma unroll
    for (int o = 1; o < 64; o <<= 1) s += __shfl_xor(s, o);
    s += rpb[start + t - ii + 6];
    sc[t] = s;
    mx = fmaxf(mx, s);
  }
  float sum = 0.f;
#pragma unroll
  for (int t = 0; t < 7; ++t) { sc[t] = __expf(sc[t] - mx); sum += sc[t]; }
  const float inv = 1.f / sum;

  float a0 = 0.f, a1 = 0.f, a2 = 0.f, a3 = 0.f;
#pragma unroll
  for (int t = 0; t < 7; ++t) {
    const int pos = r + 2 * (start + t);
    const ushort4 vv = *(const ushort4*)(base + (size_t)pos * NQKV + 2 * COUT + 4 * lane);
    const float wgt = sc[t] * inv;
    a0 += wgt * bf2f(vv.x); a1 += wgt * bf2f(vv.y);
    a2 += wgt * bf2f(vv.z); a3 += wgt * bf2f(vv.w);
  }
  *(ushort4*)(ao + ((size_t)(b * LEN + j)) * COUT + 4 * lane) =
      make_ushort4(f2bf(a0), f2bf(a1), f2bf(a2), f2bf(a3));
}

// ---------------------------------------------------------------------------
// fused proj + ds residual + double relu, gll-staged 128x128 tile.
// acc rows = l (A = activations), cols = o (B = weights); round-2 epilogue.
// ---------------------------------------------------------------------------
__global__ __launch_bounds__(256, 2) void projds_gll(
    const u16* __restrict__ ao, const u16* __restrict__ pwb,
    const float* __restrict__ pb, const u16* __restrict__ xT,
    const u16* __restrict__ dwb, const float* __restrict__ db,
    float* __restrict__ out)
{
  const int b = blockIdx.z;
  const int l0 = blockIdx.x * 128, o0 = blockIdx.y * 128;
  const int tid = threadIdx.x;
  const int w = tid >> 6, lane = tid & 63;
  const int l15 = lane & 15, kg = lane >> 4;
  const int wr = w >> 1, wc = w & 1;     // wr: l-half, wc: o-half

  __shared__ u16 sX[2][128 * 32];
  __shared__ u16 sW[2][128 * 32];

  const int arow = tid >> 2, ach = tid & 3;
  const int akey = KEY3(arow);
  const u16* aob = ao + (size_t)b * LEN * COUT;
  const u16* xTb = xT + ((size_t)b * L2V + PADW) * CIN;

  auto stage1 = [&](int s, int buf) {
#pragma unroll
    for (int i = 0; i < 2; ++i) {
      const int row = i * 64 + arow;
      const int sl = (ach ^ akey) << 3;
      gll16(aob + (size_t)(l0 + row) * COUT + (s << 5) + sl,
            (void*)&sX[buf][(i * 256 + tid) * 8]);
      gll16(pwb + (size_t)(o0 + row) * COUT + (s << 5) + sl,
            (void*)&sW[buf][(i * 256 + tid) * 8]);
    }
  };
  auto stage2 = [&](int s, int buf) {
#pragma unroll
    for (int i = 0; i < 2; ++i) {
      const int row = i * 64 + arow;
      const int sl = (ach ^ akey) << 3;
      gll16(xTb + (size_t)(l0 + row) * CIN + (s << 5) + sl,
            (void*)&sX[buf][(i * 256 + tid) * 8]);
      gll16(dwb + (size_t)(o0 + row) * CIN + (s << 5) + sl,
            (void*)&sW[buf][(i * 256 + tid) * 8]);
    }
  };

  v4f acc[4][4];
#pragma unroll
  for (int i = 0; i < 4; ++i)
#pragma unroll
    for (int j = 0; j < 4; ++j) acc[i][j] = (v4f){0.f, 0.f, 0.f, 0.f};

  stage1(0, 0);
  __syncthreads();
  for (int ss = 0; ss < 12; ++ss) {
    const int buf = ss & 1;
    if (ss < 7) stage1(ss + 1, buf ^ 1);
    else if (ss < 11) stage2(ss - 7, buf ^ 1);
    v8s a[4], bb[4];
#pragma unroll
    for (int f = 0; f < 4; ++f) {
      const int lr = wr * 64 + f * 16 + l15;
      a[f] = *(const v8s*)&sX[buf][lr * 32 + ((kg ^ KEY3(lr)) << 3)];
      const int orr = wc * 64 + f * 16 + l15;
      bb[f] = *(const v8s*)&sW[buf][orr * 32 + ((kg ^ KEY3(orr)) << 3)];
    }
    MFMA16(acc, a, bb)
    if (ss == 7) {
      // boundary: acc = relu(acc + pb[o])
#pragma unroll
      for (int fj = 0; fj < 4; ++fj) {
        const float pbv = pb[o0 + wc * 64 + fj * 16 + l15];
#pragma unroll
        for (int fi = 0; fi < 4; ++fi)
#pragma unroll
          for (int jj = 0; jj < 4; ++jj)
            acc[fi][fj][jj] = fmaxf(acc[fi][fj][jj] + pbv, 0.f);
      }
    }
    __syncthreads();
  }

  // epilogue (round-2 verbatim): +db, relu, f32 stores
  const int subl = kg;
#pragma unroll
  for (int fj = 0; fj < 4; ++fj) {
    const int o = o0 + wc * 64 + fj * 16 + l15;
    const float dbv = db[o];
    float* orow = out + ((size_t)(b * COUT + o)) * LEN;
#pragma unroll
    for (int fi = 0; fi < 4; ++fi) {
      const int lb = l0 + wr * 64 + fi * 16 + subl * 4;
      float v0 = acc[fi][fj][0] + dbv; v0 = v0 > 0.f ? v0 : 0.f;
      float v1 = acc[fi][fj][1] + dbv; v1 = v1 > 0.f ? v1 : 0.f;
      float v2 = acc[fi][fj][2] + dbv; v2 = v2 > 0.f ? v2 : 0.f;
      float v3 = acc[fi][fj][3] + dbv; v3 = v3 > 0.f ? v3 : 0.f;
      *(float4*)(orow + lb) = make_float4(v0, v1, v2, v3);
    }
  }
}

// ---------------------------------------------------------------------------
extern "C" void kernel_launch(void* const* d_in, const int* in_sizes, int n_in,
                              void* d_out, int out_size, void* d_ws, size_t ws_size,
                              hipStream_t stream)
{
  (void)in_sizes; (void)n_in; (void)out_size; (void)ws_size;
  const float* x   = (const float*)d_in[0];
  const float* c1v = (const float*)d_in[1];
  const float* c1g = (const float*)d_in[2];
  const float* c1b = (const float*)d_in[3];
  const float* qw  = (const float*)d_in[4];
  const float* qb  = (const float*)d_in[5];
  const float* rpb = (const float*)d_in[6];
  const float* pw  = (const float*)d_in[7];
  const float* pb  = (const float*)d_in[8];
  const float* dw  = (const float*)d_in[9];
  const float* db  = (const float*)d_in[10];
  float* out = (float*)d_out;

  char* ws = (char*)d_ws;
  u16* wt  = (u16*)(ws);                       // 458,752 B
  u16* qwb = (u16*)(ws + 458752);              // 393,216 B
  u16* pwb = (u16*)(ws + 851968);              // 131,072 B
  u16* dwb = (u16*)(ws + 983040);              //  65,536 B
  u16* xT  = (u16*)(ws + 1048576);             // 8,413,184 B
  u16* qkv = (u16*)(ws + 26288128);            // 50,479,104 B
  u16* ao  = (u16*)(ws + 76767232);            // 16,777,216 B

  prep_wn<<<COUT, 256, 0, stream>>>(c1v, c1g, wt);
  prep_cast<<<288, 256, 0, stream>>>(qw, pw, dw, qwb, pwb, dwb);
  zero_fill<<<336, 256, 0, stream>>>(xT, qkv, qb);
  xpose<<<dim3(LEN / 64, BATCH), 256, 0, stream>>>(x, xT);
  conv_qkv_fused<<<dim3(LEN / PTILE, BATCH), 256, 0, stream>>>(wt, xT, c1b, qwb, qb, qkv);
  attn_bf16<<<(BATCH * LEN) / 4, 256, 0, stream>>>(qkv, rpb, ao);
  projds_gll<<<dim3(LEN / 128, COUT / 128, BATCH), 256, 0, stream>>>(ao, pwb, pb, xT, dwb, db, out);
}

// Round 9
// 103.117 us; speedup vs baseline: 1.0683x; 1.0665x over previous
//
#include <hip/hip_runtime.h>
#include <math.h>

#define KW 7
#define PADW 12
#define BATCH 8
#define CIN 128
#define COUT 256
#define LEN 4096
#define L2V 4108
#define NQKV 768
#define KCONV 896
#define PTILE 64

typedef unsigned short u16;
typedef short v8s __attribute__((ext_vector_type(8)));
typedef float v4f __attribute__((ext_vector_type(4)));

// 2-bit chunk swizzle key from row bits 0..2 (keeps ds_read_b128 <=2-way)
#define KEY3(r) ((((r) & 3) ^ (((r) >> 2) & 1)))

__device__ __forceinline__ u16 f2bf(float f) {
  unsigned int x = __float_as_uint(f);
  x += 0x7fffu + ((x >> 16) & 1u);
  return (u16)(x >> 16);
}
__device__ __forceinline__ float bf2f(u16 u) {
  return __uint_as_float(((unsigned int)u) << 16);
}

__device__ __forceinline__ void gll16(const void* g, void* l) {
  __builtin_amdgcn_global_load_lds(
      (const __attribute__((address_space(1))) void*)g,
      (__attribute__((address_space(3))) void*)l, 16, 0, 0);
}

// 4(A) x 2(B) fragment MFMA cluster
#define MFMA8(ACC, AA, BB)                                                     \
  { _Pragma("unroll") for (int fi_ = 0; fi_ < 4; ++fi_)                        \
    _Pragma("unroll") for (int fj_ = 0; fj_ < 2; ++fj_)                        \
      ACC[fi_][fj_] = __builtin_amdgcn_mfma_f32_16x16x32_bf16(                 \
          AA[fi_], BB[fj_], ACC[fi_][fj_], 0, 0, 0); }

// ---------------------------------------------------------------------------
// prep 1: weight norm -> wt[c][t][ci] bf16  (k = t*128+ci contiguous per c)
// ---------------------------------------------------------------------------
__global__ __launch_bounds__(256) void prep_wn(
    const float* __restrict__ v, const float* __restrict__ g,
    u16* __restrict__ wt)
{
  const int c = blockIdx.x;
  const float* vo = v + (size_t)c * (CIN * KW);
  float s = 0.f;
  for (int i = threadIdx.x; i < CIN * KW; i += 256) { float t = vo[i]; s += t * t; }
#pragma unroll
  for (int off = 1; off < 64; off <<= 1) s += __shfl_xor(s, off);
  __shared__ float red[4];
  if ((threadIdx.x & 63) == 0) red[threadIdx.x >> 6] = s;
  __syncthreads();
  const float tot = red[0] + red[1] + red[2] + red[3];
  const float scale = g[c] / sqrtf(tot);
  for (int i = threadIdx.x; i < CIN * KW; i += 256) {
    const int ci = i / 7, t = i - ci * 7;
    wt[((size_t)c * KW + t) * CIN + ci] = f2bf(vo[i] * scale);
  }
}

// ---------------------------------------------------------------------------
// prep 2: cast qw/pw/dw to bf16
// ---------------------------------------------------------------------------
__global__ __launch_bounds__(256) void prep_cast(
    const float* __restrict__ qw, const float* __restrict__ pw,
    const float* __restrict__ dw, u16* __restrict__ qwb,
    u16* __restrict__ pwb, u16* __restrict__ dwb)
{
  const int i4 = (blockIdx.x * 256 + threadIdx.x) * 4;
  const float* src; u16* dst; int off;
  if (i4 < 196608)      { src = qw; dst = qwb; off = i4; }
  else if (i4 < 262144) { src = pw; dst = pwb; off = i4 - 196608; }
  else                  { src = dw; dst = dwb; off = i4 - 262144; }
  const float4 vv = *(const float4*)(src + off);
  *(ushort4*)(dst + off) = make_ushort4(f2bf(vv.x), f2bf(vv.y), f2bf(vv.z), f2bf(vv.w));
}

// ---------------------------------------------------------------------------
// prep 3: zero xT pad rows 0..11; fill qkv pad rows 0..11 with qb bias
// ---------------------------------------------------------------------------
__global__ __launch_bounds__(256) void zero_fill(
    u16* __restrict__ xT, u16* __restrict__ qkv, const float* __restrict__ qb)
{
  const int idx = blockIdx.x * 256 + threadIdx.x;   // < 86016
  if (idx < BATCH * PADW * CIN) {                   // 12288
    const int b = idx / (PADW * CIN), r = idx - b * (PADW * CIN);
    xT[(size_t)b * L2V * CIN + r] = 0;
  } else {
    const int k = idx - BATCH * PADW * CIN;         // < 73728
    const int b = k / (PADW * NQKV), r2 = k - b * (PADW * NQKV);
    const int row = r2 / NQKV, n = r2 - row * NQKV;
    qkv[((size_t)b * L2V + row) * NQKV + n] = f2bf(qb[n]);
  }
}

// ---------------------------------------------------------------------------
// prep 4: transpose x[b][ci][p] f32 -> xT[b][12+p][ci] bf16
// ---------------------------------------------------------------------------
__global__ __launch_bounds__(256) void xpose(const float* __restrict__ x, u16* __restrict__ xT)
{
  const int b = blockIdx.y, p0 = blockIdx.x * 64;
  const int tx = threadIdx.x & 15, ty = threadIdx.x >> 4;
  const int p = p0 + ty * 4;
  const float* xb = x + (size_t)b * CIN * LEN;
  u16* xTb = xT + (size_t)b * L2V * CIN + (size_t)(PADW + p) * CIN;
#pragma unroll
  for (int half = 0; half < 2; ++half) {
    const int ci0 = half * 64 + tx * 4;
    float r[4][4];
#pragma unroll
    for (int i = 0; i < 4; ++i)
      *(float4*)r[i] = *(const float4*)(xb + (size_t)(ci0 + i) * LEN + p);
#pragma unroll
    for (int j = 0; j < 4; ++j)
      *(ushort4*)(xTb + (size_t)j * CIN + ci0) =
          make_ushort4(f2bf(r[0][j]), f2bf(r[1][j]), f2bf(r[2][j]), f2bf(r[3][j]));
  }
}

// ---------------------------------------------------------------------------
// FUSED conv + qkv, 8 waves / 512 threads (4 waves/SIMD at 2 blocks/CU).
// Phase A: h[64p][256c] = relu(conv+bias) built in LDS (never hits HBM).
//   wave (wc = w>>1, wp = w&1) owns 64c x 32p; acc[4][2].
// Phase B: qkv[m][768] = h @ qw^T + qb; wave (wn = w>>1, wm = w&1) owns
//   64n x 32m per 256-n super-tile.
// ---------------------------------------------------------------------------
__global__ __launch_bounds__(512, 4) void conv_qkv_fused(
    const u16* __restrict__ wt, const u16* __restrict__ xT,
    const float* __restrict__ c1b, const u16* __restrict__ qwb,
    const float* __restrict__ qb, u16* __restrict__ qkv)
{
  const int b = blockIdx.y;
  const int p0 = blockIdx.x * PTILE;
  const int tid = threadIdx.x;
  const int w = tid >> 6, lane = tid & 63;
  const int l15 = lane & 15, kg = lane >> 4;
  const int wA = w >> 1, wB = w & 1;     // phase A: (c-quarter, p-half); B: (n-quarter, m-half)

  __shared__ u16 hA[PTILE * 256];       // 32 KB resident h tile (chunk-swizzled)
  __shared__ u16 sA[2][256 * 32];       // 32 KB A staging dbuf (sA[0] doubles as epilogue T)
  __shared__ u16 sB[2][PTILE * 32];     // 8 KB  B staging dbuf

  const u16* xTb = xT + (size_t)b * L2V * CIN + (size_t)p0 * CIN;

  v4f acc[4][2];
#pragma unroll
  for (int i = 0; i < 4; ++i)
#pragma unroll
    for (int j = 0; j < 2; ++j) acc[i][j] = (v4f){0.f, 0.f, 0.f, 0.f};

  // ---------------- phase A: conv, K = 896 (28 slabs of 32) ----------------
  auto stage_conv = [&](int s, int buf) {
    const int t = s >> 2, ci0 = (s & 3) << 5;
#pragma unroll
    for (int i = 0; i < 2; ++i) {
      const int cidx = i * 512 + tid;            // chunk id: row*4 + ch
      const int row = cidx >> 2, ch = cidx & 3;
      gll16(wt + (size_t)row * KCONV + t * CIN + ci0 + ((ch ^ KEY3(row)) << 3),
            (void*)&sA[buf][cidx * 8]);
    }
    if (tid < 256) {
      const int row = tid >> 2, ch = tid & 3;
      gll16(xTb + (size_t)(2 * t + row) * CIN + ci0 + ((ch ^ KEY3(row)) << 3),
            (void*)&sB[buf][tid * 8]);
    }
  };

  stage_conv(0, 0);
  __syncthreads();
  for (int s = 0; s < 28; ++s) {
    const int buf = s & 1;
    if (s < 27) stage_conv(s + 1, buf ^ 1);
    v8s a[4], bb[2];
#pragma unroll
    for (int f = 0; f < 4; ++f) {
      const int c = wA * 64 + f * 16 + l15;
      a[f] = *(const v8s*)&sA[buf][c * 32 + ((kg ^ KEY3(c)) << 3)];
    }
#pragma unroll
    for (int f = 0; f < 2; ++f) {
      const int p = wB * 32 + f * 16 + l15;
      bb[f] = *(const v8s*)&sB[buf][p * 32 + ((kg ^ KEY3(p)) << 3)];
    }
    MFMA8(acc, a, bb)
    __syncthreads();
  }

  // conv epilogue: bias+relu -> hA (swizzled: chunk32' = chunk32 ^ (p&7))
#pragma unroll
  for (int fi = 0; fi < 4; ++fi) {
    const int cb = wA * 64 + fi * 16 + kg * 4;
    const float4 bv = *(const float4*)(c1b + cb);
    const int ch32 = cb >> 3, off = cb & 7;
#pragma unroll
    for (int fj = 0; fj < 2; ++fj) {
      const int p = wB * 32 + fj * 16 + l15;
      *(ushort4*)&hA[p * 256 + ((ch32 ^ (p & 7)) << 3) + off] = make_ushort4(
          f2bf(fmaxf(acc[fi][fj][0] + bv.x, 0.f)),
          f2bf(fmaxf(acc[fi][fj][1] + bv.y, 0.f)),
          f2bf(fmaxf(acc[fi][fj][2] + bv.z, 0.f)),
          f2bf(fmaxf(acc[fi][fj][3] + bv.w, 0.f)));
      acc[fi][fj] = (v4f){0.f, 0.f, 0.f, 0.f};
    }
  }

  // ---------------- phase B: qkv, 3 super-tiles of 256 n ----------------
  auto stage_qkv = [&](int st, int s, int buf) {
#pragma unroll
    for (int i = 0; i < 2; ++i) {
      const int cidx = i * 512 + tid;
      const int row = cidx >> 2, ch = cidx & 3;
      gll16(qwb + (size_t)(st * 256 + row) * COUT + (s << 5) + ((ch ^ KEY3(row)) << 3),
            (void*)&sA[buf][cidx * 8]);
    }
  };

  const size_t mg0 = (size_t)b * L2V + PADW + p0;
  for (int st = 0; st < 3; ++st) {
    stage_qkv(st, 0, 0);
    __syncthreads();
    for (int s = 0; s < 8; ++s) {
      const int buf = s & 1;
      if (s < 7) stage_qkv(st, s + 1, buf ^ 1);
      v8s a[4], bb[2];
#pragma unroll
      for (int f = 0; f < 4; ++f) {
        const int n = wA * 64 + f * 16 + l15;
        a[f] = *(const v8s*)&sA[buf][n * 32 + ((kg ^ KEY3(n)) << 3)];
      }
#pragma unroll
      for (int f = 0; f < 2; ++f) {
        const int m = wB * 32 + f * 16 + l15;
        bb[f] = *(const v8s*)&hA[m * 256 + ((((s << 2) + kg) ^ (m & 7)) << 3)];
      }
      MFMA8(acc, a, bb)
      __syncthreads();
    }
    // ---- epilogue: two n-half passes through a 16 KB transpose buffer ----
    // T_half[m][j], m in [0,64), j in [0,128): j = wn*32 + f1*16 + kg*4,
    // global n = wn*64 + h2*32 + (j & 31).  Chunk-XOR vs (m&15).
    u16* T = &sA[0][0];
#pragma unroll
    for (int h2 = 0; h2 < 2; ++h2) {
#pragma unroll
      for (int f1 = 0; f1 < 2; ++f1) {
        const int fi = 2 * h2 + f1;
        const int j = wA * 32 + f1 * 16 + kg * 4;
        const int jc8 = j >> 3, noff = j & 7;
        const float4 bv = *(const float4*)(qb + st * 256 + wA * 64 + h2 * 32 + f1 * 16 + kg * 4);
#pragma unroll
        for (int fj = 0; fj < 2; ++fj) {
          const int m = wB * 32 + fj * 16 + l15;
          *(ushort4*)&T[m * 128 + ((jc8 ^ (m & 15)) << 3) + noff] = make_ushort4(
              f2bf(acc[fi][fj][0] + bv.x), f2bf(acc[fi][fj][1] + bv.y),
              f2bf(acc[fi][fj][2] + bv.z), f2bf(acc[fi][fj][3] + bv.w));
          acc[fi][fj] = (v4f){0.f, 0.f, 0.f, 0.f};
        }
      }
      __syncthreads();
#pragma unroll
      for (int i2 = 0; i2 < 2; ++i2) {
        const int cidx = i2 * 512 + tid;         // 1024 chunks: m*16 + j16
        const int m = cidx >> 4, j16 = cidx & 15;
        const int4 vv = *(const int4*)&T[m * 128 + ((j16 ^ (m & 15)) << 3)];
        const int n = (j16 >> 2) * 64 + h2 * 32 + (j16 & 3) * 8;
        *(int4*)(qkv + (mg0 + m) * NQKV + st * 256 + n) = vv;
      }
      __syncthreads();
    }
  }
}

// ---------------------------------------------------------------------------
// NATTEN attention on bf16 qkv. One wave per (b,j); lane owns 4 ch. (unchanged)
// ---------------------------------------------------------------------------
__global__ __launch_bounds__(256) void attn_bf16(
    const u16* __restrict__ qkv, const float* __restrict__ rpb,
    u16* __restrict__ ao)
{
  const int wid = (blockIdx.x << 2) + (threadIdx.x >> 6);
  const int lane = threadIdx.x & 63;
  const int b = wid >> 12;
  const int j = wid & 4095;
  const int r = j & 1, ii = j >> 1;
  int start = ii - 3;
  start = start < 0 ? 0 : start;
  start = start > 2047 ? 2047 : start;

  const u16* base = qkv + (size_t)b * L2V * NQKV;
  const ushort4 qv = *(const ushort4*)(base + (size_t)j * NQKV + 4 * lane);
  const float q0 = bf2f(qv.x) * 0.0625f, q1 = bf2f(qv.y) * 0.0625f;
  const float q2 = bf2f(qv.z) * 0.0625f, q3 = bf2f(qv.w) * 0.0625f;

  float sc[7];
  float mx = -1e30f;
#pragma unroll
  for (int t = 0; t < 7; ++t) {
    const int pos = r + 2 * (start + t);
    const ushort4 kv = *(const ushort4*)(base + (size_t)pos * NQKV + COUT + 4 * lane);
    float s = q0 * bf2f(kv.x) + q1 * bf2f(kv.y) + q2 * bf2f(kv.z) + q3 * bf2f(kv.w);
#pragma unroll
    for (int o = 1; o < 64; o <<= 1) s += __shfl_xor(s, o);
    s += rpb[start + t - ii + 6];
    sc[t] = s;
    mx = fmaxf(mx, s);
  }
  float sum = 0.f;
#pragma unroll
  for (int t = 0; t < 7; ++t) { sc[t] = __expf(sc[t] - mx); sum += sc[t]; }
  const float inv = 1.f / sum;

  float a0 = 0.f, a1 = 0.f, a2 = 0.f, a3 = 0.f;
#pragma unroll
  for (int t = 0; t < 7; ++t) {
    const int pos = r + 2 * (start + t);
    const ushort4 vv = *(const ushort4*)(base + (size_t)pos * NQKV + 2 * COUT + 4 * lane);
    const float wgt = sc[t] * inv;
    a0 += wgt * bf2f(vv.x); a1 += wgt * bf2f(vv.y);
    a2 += wgt * bf2f(vv.z); a3 += wgt * bf2f(vv.w);
  }
  *(ushort4*)(ao + ((size_t)(b * LEN + j)) * COUT + 4 * lane) =
      make_ushort4(f2bf(a0), f2bf(a1), f2bf(a2), f2bf(a3));
}

// ---------------------------------------------------------------------------
// fused proj + ds residual + double relu, gll-staged 128x128 tile. (unchanged)
// ---------------------------------------------------------------------------
__global__ __launch_bounds__(256, 2) void projds_gll(
    const u16* __restrict__ ao, const u16* __restrict__ pwb,
    const float* __restrict__ pb, const u16* __restrict__ xT,
    const u16* __restrict__ dwb, const float* __restrict__ db,
    float* __restrict__ out)
{
  const int b = blockIdx.z;
  const int l0 = blockIdx.x * 128, o0 = blockIdx.y * 128;
  const int tid = threadIdx.x;
  const int w = tid >> 6, lane = tid & 63;
  const int l15 = lane & 15, kg = lane >> 4;
  const int wr = w >> 1, wc = w & 1;     // wr: l-half, wc: o-half

  __shared__ u16 sX[2][128 * 32];
  __shared__ u16 sW[2][128 * 32];

  const int arow = tid >> 2, ach = tid & 3;
  const int akey = KEY3(arow);
  const u16* aob = ao + (size_t)b * LEN * COUT;
  const u16* xTb = xT + ((size_t)b * L2V + PADW) * CIN;

  auto stage1 = [&](int s, int buf) {
#pragma unroll
    for (int i = 0; i < 2; ++i) {
      const int row = i * 64 + arow;
      const int sl = (ach ^ akey) << 3;
      gll16(aob + (size_t)(l0 + row) * COUT + (s << 5) + sl,
            (void*)&sX[buf][(i * 256 + tid) * 8]);
      gll16(pwb + (size_t)(o0 + row) * COUT + (s << 5) + sl,
            (void*)&sW[buf][(i * 256 + tid) * 8]);
    }
  };
  auto stage2 = [&](int s, int buf) {
#pragma unroll
    for (int i = 0; i < 2; ++i) {
      const int row = i * 64 + arow;
      const int sl = (ach ^ akey) << 3;
      gll16(xTb + (size_t)(l0 + row) * CIN + (s << 5) + sl,
            (void*)&sX[buf][(i * 256 + tid) * 8]);
      gll16(dwb + (size_t)(o0 + row) * CIN + (s << 5) + sl,
            (void*)&sW[buf][(i * 256 + tid) * 8]);
    }
  };

  v4f acc[4][4];
#pragma unroll
  for (int i = 0; i < 4; ++i)
#pragma unroll
    for (int j = 0; j < 4; ++j) acc[i][j] = (v4f){0.f, 0.f, 0.f, 0.f};

  stage1(0, 0);
  __syncthreads();
  for (int ss = 0; ss < 12; ++ss) {
    const int buf = ss & 1;
    if (ss < 7) stage1(ss + 1, buf ^ 1);
    else if (ss < 11) stage2(ss - 7, buf ^ 1);
    v8s a[4], bb[4];
#pragma unroll
    for (int f = 0; f < 4; ++f) {
      const int lr = wr * 64 + f * 16 + l15;
      a[f] = *(const v8s*)&sX[buf][lr * 32 + ((kg ^ KEY3(lr)) << 3)];
      const int orr = wc * 64 + f * 16 + l15;
      bb[f] = *(const v8s*)&sW[buf][orr * 32 + ((kg ^ KEY3(orr)) << 3)];
    }
#pragma unroll
    for (int fi_ = 0; fi_ < 4; ++fi_)
#pragma unroll
      for (int fj_ = 0; fj_ < 4; ++fj_)
        acc[fi_][fj_] = __builtin_amdgcn_mfma_f32_16x16x32_bf16(
            a[fi_], bb[fj_], acc[fi_][fj_], 0, 0, 0);
    if (ss == 7) {
#pragma unroll
      for (int fj = 0; fj < 4; ++fj) {
        const float pbv = pb[o0 + wc * 64 + fj * 16 + l15];
#pragma unroll
        for (int fi = 0; fi < 4; ++fi)
#pragma unroll
          for (int jj = 0; jj < 4; ++jj)
            acc[fi][fj][jj] = fmaxf(acc[fi][fj][jj] + pbv, 0.f);
      }
    }
    __syncthreads();
  }

#pragma unroll
  for (int fj = 0; fj < 4; ++fj) {
    const int o = o0 + wc * 64 + fj * 16 + l15;
    const float dbv = db[o];
    float* orow = out + ((size_t)(b * COUT + o)) * LEN;
#pragma unroll
    for (int fi = 0; fi < 4; ++fi) {
      const int lb = l0 + wr * 64 + fi * 16 + kg * 4;
      float v0 = acc[fi][fj][0] + dbv; v0 = v0 > 0.f ? v0 : 0.f;
      float v1 = acc[fi][fj][1] + dbv; v1 = v1 > 0.f ? v1 : 0.f;
      float v2 = acc[fi][fj][2] + dbv; v2 = v2 > 0.f ? v2 : 0.f;
      float v3 = acc[fi][fj][3] + dbv; v3 = v3 > 0.f ? v3 : 0.f;
      *(float4*)(orow + lb) = make_float4(v0, v1, v2, v3);
    }
  }
}

// ---------------------------------------------------------------------------
extern "C" void kernel_launch(void* const* d_in, const int* in_sizes, int n_in,
                              void* d_out, int out_size, void* d_ws, size_t ws_size,
                              hipStream_t stream)
{
  (void)in_sizes; (void)n_in; (void)out_size; (void)ws_size;
  const float* x   = (const float*)d_in[0];
  const float* c1v = (const float*)d_in[1];
  const float* c1g = (const float*)d_in[2];
  const float* c1b = (const float*)d_in[3];
  const float* qw  = (const float*)d_in[4];
  const float* qb  = (const float*)d_in[5];
  const float* rpb = (const float*)d_in[6];
  const float* pw  = (const float*)d_in[7];
  const float* pb  = (const float*)d_in[8];
  const float* dw  = (const float*)d_in[9];
  const float* db  = (const float*)d_in[10];
  float* out = (float*)d_out;

  char* ws = (char*)d_ws;
  u16* wt  = (u16*)(ws);                       // 458,752 B
  u16* qwb = (u16*)(ws + 458752);              // 393,216 B
  u16* pwb = (u16*)(ws + 851968);              // 131,072 B
  u16* dwb = (u16*)(ws + 983040);              //  65,536 B
  u16* xT  = (u16*)(ws + 1048576);             // 8,413,184 B
  u16* qkv = (u16*)(ws + 26288128);            // 50,479,104 B
  u16* ao  = (u16*)(ws + 76767232);            // 16,777,216 B

  prep_wn<<<COUT, 256, 0, stream>>>(c1v, c1g, wt);
  prep_cast<<<288, 256, 0, stream>>>(qw, pw, dw, qwb, pwb, dwb);
  zero_fill<<<336, 256, 0, stream>>>(xT, qkv, qb);
  xpose<<<dim3(LEN / 64, BATCH), 256, 0, stream>>>(x, xT);
  conv_qkv_fused<<<dim3(LEN / PTILE, BATCH), 512, 0, stream>>>(wt, xT, c1b, qwb, qb, qkv);
  attn_bf16<<<(BATCH * LEN) / 4, 256, 0, stream>>>(qkv, rpb, ao);
  projds_gll<<<dim3(LEN / 128, COUT / 128, BATCH), 256, 0, stream>>>(ao, pwb, pb, xT, dwb, db, out);
}